// Round 1
// baseline (823.234 us; speedup 1.0000x reference)
//
#include <hip/hip_runtime.h>
#include <stdint.h>

#define NTOK 8192
#define DIM  1024
#define HID  2048
#define NE   8
#define CAP  17408   // 16384 slots + 8*128 max padding
#define TM 128
#define TN 128
#define TKK 64
#define LDK 72       // padded LDS k-stride (16B aligned: 72*2=144)

typedef __bf16  bf16x8  __attribute__((ext_vector_type(8)));
typedef float   floatx4 __attribute__((ext_vector_type(4)));

__device__ __forceinline__ unsigned short f2bf(float f) {
  union { float f; unsigned u; } v; v.f = f;
  unsigned r = v.u + 0x7FFFu + ((v.u >> 16) & 1u);
  return (unsigned short)(r >> 16);
}

// ---------------- cast x (fp32 -> bf16), 4 elems/thread ----------------
__global__ void cast_x_kernel(const float* __restrict__ x, unsigned short* __restrict__ xb) {
  int i = blockIdx.x * blockDim.x + threadIdx.x;
  float4 v = ((const float4*)x)[i];
  uint2 o;
  o.x = (unsigned)f2bf(v.x) | ((unsigned)f2bf(v.y) << 16);
  o.y = (unsigned)f2bf(v.z) | ((unsigned)f2bf(v.w) << 16);
  ((uint2*)xb)[i] = o;
}

// ------- transpose + cast: src[e][R][C] fp32 -> dst[e][C][R] bf16 -------
__global__ void transpose_cast_kernel(const float* __restrict__ src,
                                      unsigned short* __restrict__ dst,
                                      int R, int C) {
  __shared__ unsigned short T[64][65];
  int e = blockIdx.z;
  const float* S = src + (size_t)e * R * C;
  unsigned short* D2 = dst + (size_t)e * R * C;
  int c0 = blockIdx.x * 64;
  int r0 = blockIdx.y * 64;
  int col = threadIdx.x & 63;
  int rr  = threadIdx.x >> 6;
#pragma unroll
  for (int i = 0; i < 16; i++) {
    int r = rr + i * 4;
    T[col][r] = f2bf(S[(size_t)(r0 + r) * C + c0 + col]);
  }
  __syncthreads();
#pragma unroll
  for (int i = 0; i < 16; i++) {
    int r = rr + i * 4;
    D2[(size_t)(c0 + r) * R + r0 + col] = T[r][col];
  }
}

// ---------------- gating: one wave per token ----------------
__global__ void gating_kernel(const float* __restrict__ x, const float* __restrict__ Wg,
                              const float* __restrict__ bg, int* __restrict__ tok_e,
                              float* __restrict__ tok_g, int* __restrict__ cnt) {
  int t = blockIdx.x * 4 + (threadIdx.x >> 6);
  int lane = threadIdx.x & 63;
  float p[NE];
#pragma unroll
  for (int e = 0; e < NE; e++) p[e] = 0.f;
  const float* xr = x + (size_t)t * DIM;
  for (int d = lane; d < DIM; d += 64) {
    float xv = xr[d];
    const float* wr = Wg + (size_t)d * NE;
#pragma unroll
    for (int e = 0; e < NE; e++) p[e] += xv * wr[e];
  }
#pragma unroll
  for (int e = 0; e < NE; e++) {
#pragma unroll
    for (int off = 32; off > 0; off >>= 1) p[e] += __shfl_xor(p[e], off);
  }
  if (lane == 0) {
    float s[NE];
    float m = -1e30f;
#pragma unroll
    for (int e = 0; e < NE; e++) { s[e] = (p[e] + bg[e]) * 0.2f; m = fmaxf(m, s[e]); }
    float sum = 0.f;
#pragma unroll
    for (int e = 0; e < NE; e++) { s[e] = expf(s[e] - m); sum += s[e]; }
    float inv = 1.0f / sum;
    int i0 = 0; float v0 = -1.f;
#pragma unroll
    for (int e = 0; e < NE; e++) { float pe = s[e] * inv; if (pe > v0) { v0 = pe; i0 = e; } }
    int i1 = -1; float v1 = -1.f;
#pragma unroll
    for (int e = 0; e < NE; e++) {
      if (e == i0) continue;
      float pe = s[e] * inv; if (pe > v1) { v1 = pe; i1 = e; }
    }
    float den = v0 + v1 + 1e-9f;
    tok_e[t * 2]     = i0; tok_g[t * 2]     = v0 / den;
    tok_e[t * 2 + 1] = i1; tok_g[t * 2 + 1] = v1 / den;
    atomicAdd(&cnt[i0], 1);
    atomicAdd(&cnt[i1], 1);
  }
}

// ---------------- padded segment offsets ----------------
__global__ void offsets_kernel(const int* __restrict__ cnt, int* __restrict__ seg) {
  if (threadIdx.x == 0 && blockIdx.x == 0) {
    int s = 0;
    for (int e = 0; e < NE; e++) { seg[e] = s; s += ((cnt[e] + TM - 1) / TM) * TM; }
    seg[NE] = s;
  }
}

// ---------------- scatter tokens into slot-major order ----------------
__global__ void route_kernel(const int* __restrict__ tok_e, const float* __restrict__ tok_g,
                             const int* __restrict__ seg, int* __restrict__ cnt2,
                             int* __restrict__ token_row, float* __restrict__ gate_row) {
  int t = blockIdx.x * blockDim.x + threadIdx.x;
  if (t >= NTOK) return;
#pragma unroll
  for (int k = 0; k < 2; k++) {
    int e = tok_e[t * 2 + k];
    float g = tok_g[t * 2 + k];
    int pos = seg[e] + atomicAdd(&cnt2[e], 1);
    token_row[pos] = t;
    gate_row[pos] = g;
  }
}

// ---------------- GEMM1: h = gelu(x[slots] @ W1[e] + b1[e]) ----------------
__global__ __launch_bounds__(256)
void gemm1_kernel(const unsigned short* __restrict__ xb, const unsigned short* __restrict__ w1t,
                  const float* __restrict__ b1, const int* __restrict__ token_row,
                  const int* __restrict__ seg, unsigned short* __restrict__ hbuf) {
  __shared__ __align__(16) unsigned short As[TM * LDK];
  __shared__ __align__(16) unsigned short Bs[TN * LDK];
  int row0 = blockIdx.y * TM;
  int total = seg[NE];
  if (row0 >= total) return;
  int e = 0;
  while (row0 >= seg[e + 1]) e++;
  int n0 = blockIdx.x * TN;
  int tid = threadIdx.x;
  int lane = tid & 63;
  int wm = tid >> 7;
  int wn = (tid >> 6) & 1;

  floatx4 zero4 = {0.f, 0.f, 0.f, 0.f};
  floatx4 acc[4][4];
#pragma unroll
  for (int a = 0; a < 4; a++)
#pragma unroll
    for (int b = 0; b < 4; b++) acc[a][b] = zero4;

  int rbase = tid >> 3;         // 0..31
  int colseg = (tid & 7) * 8;   // k offset within tile
  int trow[4];
#pragma unroll
  for (int i = 0; i < 4; i++) trow[i] = token_row[row0 + rbase + i * 32];

  const unsigned short* w1e = w1t + (size_t)e * DIM * HID;

  for (int k0 = 0; k0 < DIM; k0 += TKK) {
#pragma unroll
    for (int i = 0; i < 4; i++) {
      int r = rbase + i * 32;
      uint4 v = {0u, 0u, 0u, 0u};
      int t = trow[i];
      if (t >= 0) v = *(const uint4*)(xb + (size_t)t * DIM + k0 + colseg);
      *(uint4*)&As[r * LDK + colseg] = v;
      uint4 w = *(const uint4*)(w1e + (size_t)(n0 + r) * DIM + k0 + colseg);
      *(uint4*)&Bs[r * LDK + colseg] = w;
    }
    __syncthreads();
    int mr = lane & 15;
    int kq = (lane >> 4) * 8;
#pragma unroll
    for (int kk = 0; kk < TKK; kk += 32) {
      bf16x8 af[4], bfr[4];
#pragma unroll
      for (int im = 0; im < 4; im++)
        af[im] = *(const bf16x8*)&As[(wm * 64 + im * 16 + mr) * LDK + kk + kq];
#pragma unroll
      for (int in = 0; in < 4; in++)
        bfr[in] = *(const bf16x8*)&Bs[(wn * 64 + in * 16 + mr) * LDK + kk + kq];
#pragma unroll
      for (int im = 0; im < 4; im++)
#pragma unroll
        for (int in = 0; in < 4; in++)
          acc[im][in] = __builtin_amdgcn_mfma_f32_16x16x32_bf16(af[im], bfr[in], acc[im][in], 0, 0, 0);
    }
    __syncthreads();
  }
  int quad = lane >> 4;
  int c16 = lane & 15;
  const float* b1e = b1 + e * HID;
#pragma unroll
  for (int im = 0; im < 4; im++) {
    int rb = row0 + wm * 64 + im * 16 + quad * 4;
#pragma unroll
    for (int in = 0; in < 4; in++) {
      int c = n0 + wn * 64 + in * 16 + c16;
      float bias = b1e[c];
#pragma unroll
      for (int i = 0; i < 4; i++) {
        float v = acc[im][in][i] + bias;
        v = 0.5f * v * (1.0f + erff(v * 0.70710678118654752f));
        hbuf[(size_t)(rb + i) * HID + c] = f2bf(v);
      }
    }
  }
}

// ---------------- GEMM2: y[token] += gate * (h @ W2[e] + b2[e]) ----------------
__global__ __launch_bounds__(256)
void gemm2_kernel(const unsigned short* __restrict__ hbuf, const unsigned short* __restrict__ w2t,
                  const float* __restrict__ b2, const int* __restrict__ token_row,
                  const float* __restrict__ gate_row, const int* __restrict__ seg,
                  float* __restrict__ y) {
  __shared__ __align__(16) unsigned short As[TM * LDK];
  __shared__ __align__(16) unsigned short Bs[TN * LDK];
  int row0 = blockIdx.y * TM;
  int total = seg[NE];
  if (row0 >= total) return;
  int e = 0;
  while (row0 >= seg[e + 1]) e++;
  int n0 = blockIdx.x * TN;
  int tid = threadIdx.x;
  int lane = tid & 63;
  int wm = tid >> 7;
  int wn = (tid >> 6) & 1;

  floatx4 zero4 = {0.f, 0.f, 0.f, 0.f};
  floatx4 acc[4][4];
#pragma unroll
  for (int a = 0; a < 4; a++)
#pragma unroll
    for (int b = 0; b < 4; b++) acc[a][b] = zero4;

  int rbase = tid >> 3;
  int colseg = (tid & 7) * 8;

  const unsigned short* w2e = w2t + (size_t)e * DIM * HID;

  for (int k0 = 0; k0 < HID; k0 += TKK) {
#pragma unroll
    for (int i = 0; i < 4; i++) {
      int r = rbase + i * 32;
      uint4 v = *(const uint4*)(hbuf + (size_t)(row0 + r) * HID + k0 + colseg);
      *(uint4*)&As[r * LDK + colseg] = v;
      uint4 w = *(const uint4*)(w2e + (size_t)(n0 + r) * HID + k0 + colseg);
      *(uint4*)&Bs[r * LDK + colseg] = w;
    }
    __syncthreads();
    int mr = lane & 15;
    int kq = (lane >> 4) * 8;
#pragma unroll
    for (int kk = 0; kk < TKK; kk += 32) {
      bf16x8 af[4], bfr[4];
#pragma unroll
      for (int im = 0; im < 4; im++)
        af[im] = *(const bf16x8*)&As[(wm * 64 + im * 16 + mr) * LDK + kk + kq];
#pragma unroll
      for (int in = 0; in < 4; in++)
        bfr[in] = *(const bf16x8*)&Bs[(wn * 64 + in * 16 + mr) * LDK + kk + kq];
#pragma unroll
      for (int im = 0; im < 4; im++)
#pragma unroll
        for (int in = 0; in < 4; in++)
          acc[im][in] = __builtin_amdgcn_mfma_f32_16x16x32_bf16(af[im], bfr[in], acc[im][in], 0, 0, 0);
    }
    __syncthreads();
  }
  int quad = lane >> 4;
  int c16 = lane & 15;
  const float* b2e = b2 + e * DIM;
#pragma unroll
  for (int im = 0; im < 4; im++) {
    int rb = row0 + wm * 64 + im * 16 + quad * 4;
    int tks[4]; float gs[4];
#pragma unroll
    for (int i = 0; i < 4; i++) { tks[i] = token_row[rb + i]; gs[i] = gate_row[rb + i]; }
#pragma unroll
    for (int in = 0; in < 4; in++) {
      int c = n0 + wn * 64 + in * 16 + c16;
      float bias = b2e[c];
#pragma unroll
      for (int i = 0; i < 4; i++) {
        if (tks[i] >= 0) {
          float val = gs[i] * (acc[im][in][i] + bias);
          atomicAdd(&y[(size_t)tks[i] * DIM + c], val);
        }
      }
    }
  }
}

// ---------------- launch ----------------
extern "C" void kernel_launch(void* const* d_in, const int* in_sizes, int n_in,
                              void* d_out, int out_size, void* d_ws, size_t ws_size,
                              hipStream_t stream) {
  const float* x  = (const float*)d_in[0];
  const float* Wg = (const float*)d_in[1];
  const float* bg = (const float*)d_in[2];
  const float* W1 = (const float*)d_in[3];
  const float* b1 = (const float*)d_in[4];
  const float* W2 = (const float*)d_in[5];
  const float* b2 = (const float*)d_in[6];
  float* y = (float*)d_out;
  char* ws = (char*)d_ws;

  constexpr size_t OFF_META = 0;                                  // cnt@0, cnt2@64, seg@128
  constexpr size_t OFF_TOKE = 256;
  constexpr size_t OFF_TOKG = OFF_TOKE + (size_t)NTOK * 2 * 4;
  constexpr size_t OFF_TROW = OFF_TOKG + (size_t)NTOK * 2 * 4;
  constexpr size_t OFF_GROW = OFF_TROW + (size_t)CAP * 4;
  constexpr size_t OFF_XB   = OFF_GROW + (size_t)CAP * 4;
  constexpr size_t OFF_W1T  = OFF_XB  + (size_t)NTOK * DIM * 2;
  constexpr size_t OFF_W2T  = OFF_W1T + (size_t)NE * DIM * HID * 2;
  constexpr size_t OFF_H    = OFF_W2T + (size_t)NE * DIM * HID * 2;

  int* cnt        = (int*)(ws + OFF_META);
  int* cnt2       = (int*)(ws + OFF_META + 64);
  int* seg        = (int*)(ws + OFF_META + 128);
  int* tok_e      = (int*)(ws + OFF_TOKE);
  float* tok_g    = (float*)(ws + OFF_TOKG);
  int* token_row  = (int*)(ws + OFF_TROW);
  float* gate_row = (float*)(ws + OFF_GROW);
  unsigned short* xb   = (unsigned short*)(ws + OFF_XB);
  unsigned short* w1t  = (unsigned short*)(ws + OFF_W1T);
  unsigned short* w2t  = (unsigned short*)(ws + OFF_W2T);
  unsigned short* hbuf = (unsigned short*)(ws + OFF_H);

  hipMemsetAsync(ws, 0, 192, stream);                       // cnt, cnt2
  hipMemsetAsync(token_row, 0xFF, (size_t)CAP * 4, stream); // token_row = -1
  hipMemsetAsync(y, 0, (size_t)NTOK * DIM * 4, stream);

  cast_x_kernel<<<NTOK * DIM / 4 / 256, 256, 0, stream>>>(x, xb);
  transpose_cast_kernel<<<dim3(HID / 64, DIM / 64, NE), 256, 0, stream>>>(W1, w1t, DIM, HID);
  transpose_cast_kernel<<<dim3(DIM / 64, HID / 64, NE), 256, 0, stream>>>(W2, w2t, HID, DIM);
  gating_kernel<<<NTOK / 4, 256, 0, stream>>>(x, Wg, bg, tok_e, tok_g, cnt);
  offsets_kernel<<<1, 64, 0, stream>>>(cnt, seg);
  route_kernel<<<NTOK / 256, 256, 0, stream>>>(tok_e, tok_g, seg, cnt2, token_row, gate_row);
  gemm1_kernel<<<dim3(HID / TN, CAP / TM), 256, 0, stream>>>(xb, w1t, b1, token_row, seg, hbuf);
  gemm2_kernel<<<dim3(DIM / TN, CAP / TM), 256, 0, stream>>>(hbuf, w2t, b2, token_row, gate_row, seg, y);
}

// Round 2
// 765.321 us; speedup vs baseline: 1.0757x; 1.0757x over previous
//
#include <hip/hip_runtime.h>
#include <stdint.h>

#define NTOK 8192
#define DIM  1024
#define HID  2048
#define NE   8
#define CAP  17408   // 16384 slots + 8*128 max padding
#define TM 128
#define TN 128
#define TKK 64       // k elems per tile; row = 128 B (unpadded, required by global_load_lds)

typedef __bf16  bf16x8  __attribute__((ext_vector_type(8)));
typedef float   floatx4 __attribute__((ext_vector_type(4)));

__device__ __forceinline__ unsigned short f2bf(float f) {
  union { float f; unsigned u; } v; v.f = f;
  unsigned r = v.u + 0x7FFFu + ((v.u >> 16) & 1u);
  return (unsigned short)(r >> 16);
}

__device__ __forceinline__ void async_ld16(const unsigned short* g, unsigned short* l) {
  __builtin_amdgcn_global_load_lds(
      (const __attribute__((address_space(1))) unsigned int*)(const void*)g,
      (__attribute__((address_space(3))) unsigned int*)(void*)l, 16, 0, 0);
}

// ---------------- cast x (fp32 -> bf16), 4 elems/thread ----------------
__global__ void cast_x_kernel(const float* __restrict__ x, unsigned short* __restrict__ xb) {
  int i = blockIdx.x * blockDim.x + threadIdx.x;
  float4 v = ((const float4*)x)[i];
  uint2 o;
  o.x = (unsigned)f2bf(v.x) | ((unsigned)f2bf(v.y) << 16);
  o.y = (unsigned)f2bf(v.z) | ((unsigned)f2bf(v.w) << 16);
  ((uint2*)xb)[i] = o;
}

// ------- transpose + cast: src[e][R][C] fp32 -> dst[e][C][R] bf16 -------
__global__ void transpose_cast_kernel(const float* __restrict__ src,
                                      unsigned short* __restrict__ dst,
                                      int R, int C) {
  __shared__ unsigned short T[64][65];
  int e = blockIdx.z;
  const float* S = src + (size_t)e * R * C;
  unsigned short* D2 = dst + (size_t)e * R * C;
  int c0 = blockIdx.x * 64;
  int r0 = blockIdx.y * 64;
  int col = threadIdx.x & 63;
  int rr  = threadIdx.x >> 6;
#pragma unroll
  for (int i = 0; i < 16; i++) {
    int r = rr + i * 4;
    T[col][r] = f2bf(S[(size_t)(r0 + r) * C + c0 + col]);
  }
  __syncthreads();
#pragma unroll
  for (int i = 0; i < 16; i++) {
    int r = rr + i * 4;
    D2[(size_t)(c0 + r) * R + r0 + col] = T[r][col];
  }
}

// ---------------- gating: one wave per token ----------------
__global__ void gating_kernel(const float* __restrict__ x, const float* __restrict__ Wg,
                              const float* __restrict__ bg, int* __restrict__ tok_e,
                              float* __restrict__ tok_g, int* __restrict__ cnt) {
  int t = blockIdx.x * 4 + (threadIdx.x >> 6);
  int lane = threadIdx.x & 63;
  float p[NE];
#pragma unroll
  for (int e = 0; e < NE; e++) p[e] = 0.f;
  const float* xr = x + (size_t)t * DIM;
  for (int d = lane; d < DIM; d += 64) {
    float xv = xr[d];
    const float* wr = Wg + (size_t)d * NE;
#pragma unroll
    for (int e = 0; e < NE; e++) p[e] += xv * wr[e];
  }
#pragma unroll
  for (int e = 0; e < NE; e++) {
#pragma unroll
    for (int off = 32; off > 0; off >>= 1) p[e] += __shfl_xor(p[e], off);
  }
  if (lane == 0) {
    float s[NE];
    float m = -1e30f;
#pragma unroll
    for (int e = 0; e < NE; e++) { s[e] = (p[e] + bg[e]) * 0.2f; m = fmaxf(m, s[e]); }
    float sum = 0.f;
#pragma unroll
    for (int e = 0; e < NE; e++) { s[e] = expf(s[e] - m); sum += s[e]; }
    float inv = 1.0f / sum;
    int i0 = 0; float v0 = -1.f;
#pragma unroll
    for (int e = 0; e < NE; e++) { float pe = s[e] * inv; if (pe > v0) { v0 = pe; i0 = e; } }
    int i1 = -1; float v1 = -1.f;
#pragma unroll
    for (int e = 0; e < NE; e++) {
      if (e == i0) continue;
      float pe = s[e] * inv; if (pe > v1) { v1 = pe; i1 = e; }
    }
    float den = v0 + v1 + 1e-9f;
    tok_e[t * 2]     = i0; tok_g[t * 2]     = v0 / den;
    tok_e[t * 2 + 1] = i1; tok_g[t * 2 + 1] = v1 / den;
    atomicAdd(&cnt[i0], 1);
    atomicAdd(&cnt[i1], 1);
  }
}

// ---------------- padded segment offsets ----------------
__global__ void offsets_kernel(const int* __restrict__ cnt, int* __restrict__ seg) {
  if (threadIdx.x == 0 && blockIdx.x == 0) {
    int s = 0;
    for (int e = 0; e < NE; e++) { seg[e] = s; s += ((cnt[e] + TM - 1) / TM) * TM; }
    seg[NE] = s;
  }
}

// ---------------- scatter tokens into slot-major order ----------------
__global__ void route_kernel(const int* __restrict__ tok_e, const float* __restrict__ tok_g,
                             const int* __restrict__ seg, int* __restrict__ cnt2,
                             int* __restrict__ token_row, float* __restrict__ gate_row,
                             int* __restrict__ tok_pos) {
  int t = blockIdx.x * blockDim.x + threadIdx.x;
  if (t >= NTOK) return;
#pragma unroll
  for (int k = 0; k < 2; k++) {
    int e = tok_e[t * 2 + k];
    float g = tok_g[t * 2 + k];
    int pos = seg[e] + atomicAdd(&cnt2[e], 1);
    token_row[pos] = t;
    gate_row[pos] = g;
    tok_pos[t * 2 + k] = pos;
  }
}

// ---------------- GEMM1: h = gelu(x[slots] @ W1[e] + b1[e]) ----------------
__global__ __launch_bounds__(256)
void gemm1_kernel(const unsigned short* __restrict__ xb, const unsigned short* __restrict__ w1t,
                  const float* __restrict__ b1, const int* __restrict__ token_row,
                  const int* __restrict__ seg, const unsigned short* __restrict__ zbuf,
                  unsigned short* __restrict__ hbuf) {
  __shared__ __align__(16) unsigned short As[TM * TKK];
  __shared__ __align__(16) unsigned short Bs[TN * TKK];
  int row0 = blockIdx.y * TM;
  int total = seg[NE];
  if (row0 >= total) return;
  int e = 0;
  while (row0 >= seg[e + 1]) e++;
  int n0 = blockIdx.x * TN;
  int tid = threadIdx.x;
  int lane = tid & 63;
  int w = tid >> 6;
  int wm = tid >> 7;
  int wn = (tid >> 6) & 1;
  int lrow = lane >> 3;       // 0..7
  int lk   = (lane & 7) * 8;  // element offset within 64-elem row

  floatx4 zero4 = {0.f, 0.f, 0.f, 0.f};
  floatx4 acc[4][4];
#pragma unroll
  for (int a = 0; a < 4; a++)
#pragma unroll
    for (int b = 0; b < 4; b++) acc[a][b] = zero4;

  const unsigned short* w1e = w1t + (size_t)e * DIM * HID;
  const unsigned short* srcA[4];
  const unsigned short* srcB[4];
#pragma unroll
  for (int i = 0; i < 4; i++) {
    int r = w * 32 + i * 8 + lrow;
    int t = token_row[row0 + r];
    srcA[i] = (t >= 0 ? xb + (size_t)t * DIM : zbuf) + lk;
    srcB[i] = w1e + (size_t)(n0 + r) * DIM + lk;
  }

  int mr = lane & 15;
  int kq = (lane >> 4) * 8;

  for (int k0 = 0; k0 < DIM; k0 += TKK) {
#pragma unroll
    for (int i = 0; i < 4; i++) {
      async_ld16(srcA[i] + k0, &As[(w * 32 + i * 8 + lrow) * TKK + lk]);
      async_ld16(srcB[i] + k0, &Bs[(w * 32 + i * 8 + lrow) * TKK + lk]);
    }
    __syncthreads();
#pragma unroll
    for (int kk = 0; kk < TKK; kk += 32) {
      bf16x8 af[4], bfr[4];
#pragma unroll
      for (int im = 0; im < 4; im++)
        af[im] = *(const bf16x8*)&As[(wm * 64 + im * 16 + mr) * TKK + kk + kq];
#pragma unroll
      for (int in = 0; in < 4; in++)
        bfr[in] = *(const bf16x8*)&Bs[(wn * 64 + in * 16 + mr) * TKK + kk + kq];
#pragma unroll
      for (int im = 0; im < 4; im++)
#pragma unroll
        for (int in = 0; in < 4; in++)
          acc[im][in] = __builtin_amdgcn_mfma_f32_16x16x32_bf16(af[im], bfr[in], acc[im][in], 0, 0, 0);
    }
    __syncthreads();
  }
  int quad = lane >> 4;
  int c16 = lane & 15;
  const float* b1e = b1 + e * HID;
#pragma unroll
  for (int im = 0; im < 4; im++) {
    int rb = row0 + wm * 64 + im * 16 + quad * 4;
#pragma unroll
    for (int in = 0; in < 4; in++) {
      int c = n0 + wn * 64 + in * 16 + c16;
      float bias = b1e[c];
#pragma unroll
      for (int i = 0; i < 4; i++) {
        float v = acc[im][in][i] + bias;
        v = 0.5f * v * (1.0f + erff(v * 0.70710678118654752f));
        hbuf[(size_t)(rb + i) * HID + c] = f2bf(v);
      }
    }
  }
}

// ---------------- GEMM2: obuf[slot] = gate * (h @ W2[e] + b2[e]) ----------------
__global__ __launch_bounds__(256)
void gemm2_kernel(const unsigned short* __restrict__ hbuf, const unsigned short* __restrict__ w2t,
                  const float* __restrict__ b2, const float* __restrict__ gate_row,
                  const int* __restrict__ seg, unsigned short* __restrict__ obuf) {
  __shared__ __align__(16) unsigned short As[TM * TKK];
  __shared__ __align__(16) unsigned short Bs[TN * TKK];
  int row0 = blockIdx.y * TM;
  int total = seg[NE];
  if (row0 >= total) return;
  int e = 0;
  while (row0 >= seg[e + 1]) e++;
  int n0 = blockIdx.x * TN;
  int tid = threadIdx.x;
  int lane = tid & 63;
  int w = tid >> 6;
  int wm = tid >> 7;
  int wn = (tid >> 6) & 1;
  int lrow = lane >> 3;
  int lk   = (lane & 7) * 8;

  floatx4 zero4 = {0.f, 0.f, 0.f, 0.f};
  floatx4 acc[4][4];
#pragma unroll
  for (int a = 0; a < 4; a++)
#pragma unroll
    for (int b = 0; b < 4; b++) acc[a][b] = zero4;

  const unsigned short* w2e = w2t + (size_t)e * DIM * HID;
  const unsigned short* srcA[4];
  const unsigned short* srcB[4];
#pragma unroll
  for (int i = 0; i < 4; i++) {
    int r = w * 32 + i * 8 + lrow;
    srcA[i] = hbuf + (size_t)(row0 + r) * HID + lk;
    srcB[i] = w2e + (size_t)(n0 + r) * HID + lk;
  }

  int mr = lane & 15;
  int kq = (lane >> 4) * 8;

  for (int k0 = 0; k0 < HID; k0 += TKK) {
#pragma unroll
    for (int i = 0; i < 4; i++) {
      async_ld16(srcA[i] + k0, &As[(w * 32 + i * 8 + lrow) * TKK + lk]);
      async_ld16(srcB[i] + k0, &Bs[(w * 32 + i * 8 + lrow) * TKK + lk]);
    }
    __syncthreads();
#pragma unroll
    for (int kk = 0; kk < TKK; kk += 32) {
      bf16x8 af[4], bfr[4];
#pragma unroll
      for (int im = 0; im < 4; im++)
        af[im] = *(const bf16x8*)&As[(wm * 64 + im * 16 + mr) * TKK + kk + kq];
#pragma unroll
      for (int in = 0; in < 4; in++)
        bfr[in] = *(const bf16x8*)&Bs[(wn * 64 + in * 16 + mr) * TKK + kk + kq];
#pragma unroll
      for (int im = 0; im < 4; im++)
#pragma unroll
        for (int in = 0; in < 4; in++)
          acc[im][in] = __builtin_amdgcn_mfma_f32_16x16x32_bf16(af[im], bfr[in], acc[im][in], 0, 0, 0);
    }
    __syncthreads();
  }
  int quad = lane >> 4;
  int c16 = lane & 15;
  const float* b2e = b2 + e * DIM;
#pragma unroll
  for (int im = 0; im < 4; im++) {
    int rb = row0 + wm * 64 + im * 16 + quad * 4;
    float gs[4];
#pragma unroll
    for (int i = 0; i < 4; i++) gs[i] = gate_row[rb + i];
#pragma unroll
    for (int in = 0; in < 4; in++) {
      int c = n0 + wn * 64 + in * 16 + c16;
      float bias = b2e[c];
#pragma unroll
      for (int i = 0; i < 4; i++) {
        float val = gs[i] * (acc[im][in][i] + bias);
        obuf[(size_t)(rb + i) * DIM + c] = f2bf(val);
      }
    }
  }
}

// ---------------- combine: y[t] = obuf[pos0] + obuf[pos1] ----------------
__global__ void combine_kernel(const unsigned short* __restrict__ obuf,
                               const int* __restrict__ tok_pos,
                               float* __restrict__ y) {
  int idx = blockIdx.x * 256 + threadIdx.x;
  int t = idx >> 7;            // DIM/8 = 128 chunks per token
  int c = (idx & 127) << 3;
  int p0 = tok_pos[t * 2];
  int p1 = tok_pos[t * 2 + 1];
  uint4 a = *(const uint4*)(obuf + (size_t)p0 * DIM + c);
  uint4 b = *(const uint4*)(obuf + (size_t)p1 * DIM + c);
  float out[8];
  unsigned au[4] = {a.x, a.y, a.z, a.w};
  unsigned bu[4] = {b.x, b.y, b.z, b.w};
#pragma unroll
  for (int i = 0; i < 4; i++) {
    union { unsigned u; float f; } lo0, hi0, lo1, hi1;
    lo0.u = au[i] << 16; hi0.u = au[i] & 0xFFFF0000u;
    lo1.u = bu[i] << 16; hi1.u = bu[i] & 0xFFFF0000u;
    out[i * 2]     = lo0.f + lo1.f;
    out[i * 2 + 1] = hi0.f + hi1.f;
  }
  float* yp = y + (size_t)t * DIM + c;
  *(float4*)yp       = *(float4*)&out[0];
  *(float4*)(yp + 4) = *(float4*)&out[4];
}

// ---------------- launch ----------------
extern "C" void kernel_launch(void* const* d_in, const int* in_sizes, int n_in,
                              void* d_out, int out_size, void* d_ws, size_t ws_size,
                              hipStream_t stream) {
  const float* x  = (const float*)d_in[0];
  const float* Wg = (const float*)d_in[1];
  const float* bg = (const float*)d_in[2];
  const float* W1 = (const float*)d_in[3];
  const float* b1 = (const float*)d_in[4];
  const float* W2 = (const float*)d_in[5];
  const float* b2 = (const float*)d_in[6];
  float* y = (float*)d_out;
  char* ws = (char*)d_ws;

  constexpr size_t OFF_META = 0;                                  // cnt@0, cnt2@64, seg@128
  constexpr size_t OFF_TOKE = 256;
  constexpr size_t OFF_TOKG = OFF_TOKE + (size_t)NTOK * 2 * 4;
  constexpr size_t OFF_TPOS = OFF_TOKG + (size_t)NTOK * 2 * 4;
  constexpr size_t OFF_TROW = OFF_TPOS + (size_t)NTOK * 2 * 4;
  constexpr size_t OFF_GROW = OFF_TROW + (size_t)CAP * 4;
  constexpr size_t OFF_ZB   = OFF_GROW + (size_t)CAP * 4;
  constexpr size_t OFF_XB   = OFF_ZB  + (size_t)DIM * 2;
  constexpr size_t OFF_W1T  = OFF_XB  + (size_t)NTOK * DIM * 2;
  constexpr size_t OFF_W2T  = OFF_W1T + (size_t)NE * DIM * HID * 2;
  constexpr size_t OFF_H    = OFF_W2T + (size_t)NE * DIM * HID * 2;
  // obuf aliases xb+w1t (both dead before gemm2 runs): needs CAP*DIM*2 = 35.7MB < 50.2MB
  constexpr size_t OFF_OBUF = OFF_XB;

  int* cnt        = (int*)(ws + OFF_META);
  int* cnt2       = (int*)(ws + OFF_META + 64);
  int* seg        = (int*)(ws + OFF_META + 128);
  int* tok_e      = (int*)(ws + OFF_TOKE);
  float* tok_g    = (float*)(ws + OFF_TOKG);
  int* tok_pos    = (int*)(ws + OFF_TPOS);
  int* token_row  = (int*)(ws + OFF_TROW);
  float* gate_row = (float*)(ws + OFF_GROW);
  unsigned short* zbuf = (unsigned short*)(ws + OFF_ZB);
  unsigned short* xb   = (unsigned short*)(ws + OFF_XB);
  unsigned short* w1t  = (unsigned short*)(ws + OFF_W1T);
  unsigned short* w2t  = (unsigned short*)(ws + OFF_W2T);
  unsigned short* hbuf = (unsigned short*)(ws + OFF_H);
  unsigned short* obuf = (unsigned short*)(ws + OFF_OBUF);

  hipMemsetAsync(ws, 0, 192, stream);                       // cnt, cnt2
  hipMemsetAsync(token_row, 0xFF, (size_t)CAP * 4, stream); // token_row = -1
  hipMemsetAsync(zbuf, 0, (size_t)DIM * 2, stream);         // zero row for padding slots

  cast_x_kernel<<<NTOK * DIM / 4 / 256, 256, 0, stream>>>(x, xb);
  transpose_cast_kernel<<<dim3(HID / 64, DIM / 64, NE), 256, 0, stream>>>(W1, w1t, DIM, HID);
  transpose_cast_kernel<<<dim3(DIM / 64, HID / 64, NE), 256, 0, stream>>>(W2, w2t, HID, DIM);
  gating_kernel<<<NTOK / 4, 256, 0, stream>>>(x, Wg, bg, tok_e, tok_g, cnt);
  offsets_kernel<<<1, 64, 0, stream>>>(cnt, seg);
  route_kernel<<<NTOK / 256, 256, 0, stream>>>(tok_e, tok_g, seg, cnt2, token_row, gate_row, tok_pos);
  gemm1_kernel<<<dim3(HID / TN, CAP / TM), 256, 0, stream>>>(xb, w1t, b1, token_row, seg, zbuf, hbuf);
  gemm2_kernel<<<dim3(DIM / TN, CAP / TM), 256, 0, stream>>>(hbuf, w2t, b2, gate_row, seg, obuf);
  combine_kernel<<<NTOK * DIM / 8 / 256, 256, 0, stream>>>(obuf, tok_pos, y);
}

// Round 3
// 738.875 us; speedup vs baseline: 1.1142x; 1.0358x over previous
//
#include <hip/hip_runtime.h>
#include <stdint.h>

#define NTOK 8192
#define DIM  1024
#define HID  2048
#define NE   8
#define CAP  17408   // 16384 slots + 8*128 max padding
#define TM 128
#define TN 128
#define TKK 64       // k elems per tile; row = 128 B (unpadded, required by global_load_lds)

typedef __bf16  bf16x8  __attribute__((ext_vector_type(8)));
typedef float   floatx4 __attribute__((ext_vector_type(4)));

__device__ __forceinline__ unsigned short f2bf(float f) {
  union { float f; unsigned u; } v; v.f = f;
  unsigned r = v.u + 0x7FFFu + ((v.u >> 16) & 1u);
  return (unsigned short)(r >> 16);
}

__device__ __forceinline__ void async_ld16(const unsigned short* g, unsigned short* l) {
  __builtin_amdgcn_global_load_lds(
      (const __attribute__((address_space(1))) unsigned int*)(const void*)g,
      (__attribute__((address_space(3))) unsigned int*)(void*)l, 16, 0, 0);
}

// ------- transpose + cast: src[e][R][C] fp32 -> dst[e][C][R] bf16 -------
__global__ void transpose_cast_kernel(const float* __restrict__ src,
                                      unsigned short* __restrict__ dst,
                                      int R, int C) {
  __shared__ unsigned short T[64][65];
  int e = blockIdx.z;
  const float* S = src + (size_t)e * R * C;
  unsigned short* D2 = dst + (size_t)e * R * C;
  int c0 = blockIdx.x * 64;
  int r0 = blockIdx.y * 64;
  int col = threadIdx.x & 63;
  int rr  = threadIdx.x >> 6;
#pragma unroll
  for (int i = 0; i < 16; i++) {
    int r = rr + i * 4;
    T[col][r] = f2bf(S[(size_t)(r0 + r) * C + c0 + col]);
  }
  __syncthreads();
#pragma unroll
  for (int i = 0; i < 16; i++) {
    int r = rr + i * 4;
    D2[(size_t)(c0 + r) * R + r0 + col] = T[r][col];
  }
}

// ------- gating v2: LDS-staged transposed Wg, fused x->bf16 cast -------
// 1024 blocks x 256 threads; 8 tokens/block, 2 tokens/wave.
__global__ __launch_bounds__(256)
void gating_kernel(const float* __restrict__ x, const float* __restrict__ Wg,
                   const float* __restrict__ bg, int* __restrict__ tok_e,
                   float* __restrict__ tok_g, int* __restrict__ cnt,
                   unsigned short* __restrict__ xb) {
  __shared__ float WgS[NE * DIM];   // transposed [e][d], 32 KB
  int tid = threadIdx.x;
#pragma unroll
  for (int j = 0; j < NE * DIM / 256; j++) {   // 32 iters
    int i = j * 256 + tid;
    WgS[(i & 7) * DIM + (i >> 3)] = Wg[i];     // Wg is [d][e] row-major
  }
  __syncthreads();
  int wave = tid >> 6;
  int lane = tid & 63;
#pragma unroll
  for (int ti = 0; ti < 2; ti++) {
    int t = blockIdx.x * 8 + wave * 2 + ti;
    const float* xr = x + (size_t)t * DIM;
    float p[NE];
#pragma unroll
    for (int e = 0; e < NE; e++) p[e] = 0.f;
#pragma unroll
    for (int it = 0; it < DIM / 256; it++) {   // 4 iters, float4 per lane
      int d = (it * 64 + lane) * 4;
      float4 xv = *(const float4*)&xr[d];
      uint2 o;
      o.x = (unsigned)f2bf(xv.x) | ((unsigned)f2bf(xv.y) << 16);
      o.y = (unsigned)f2bf(xv.z) | ((unsigned)f2bf(xv.w) << 16);
      *(uint2*)&xb[(size_t)t * DIM + d] = o;
#pragma unroll
      for (int e = 0; e < NE; e++) {
        float4 wv = *(const float4*)&WgS[e * DIM + d];
        p[e] += xv.x * wv.x + xv.y * wv.y + xv.z * wv.z + xv.w * wv.w;
      }
    }
#pragma unroll
    for (int e = 0; e < NE; e++) {
#pragma unroll
      for (int off = 32; off > 0; off >>= 1) p[e] += __shfl_xor(p[e], off);
    }
    if (lane == 0) {
      float s[NE];
      float m = -1e30f;
#pragma unroll
      for (int e = 0; e < NE; e++) { s[e] = (p[e] + bg[e]) * 0.2f; m = fmaxf(m, s[e]); }
      float sum = 0.f;
#pragma unroll
      for (int e = 0; e < NE; e++) { s[e] = expf(s[e] - m); sum += s[e]; }
      float inv = 1.0f / sum;
      int i0 = 0; float v0 = -1.f;
#pragma unroll
      for (int e = 0; e < NE; e++) { float pe = s[e] * inv; if (pe > v0) { v0 = pe; i0 = e; } }
      int i1 = -1; float v1 = -1.f;
#pragma unroll
      for (int e = 0; e < NE; e++) {
        if (e == i0) continue;
        float pe = s[e] * inv; if (pe > v1) { v1 = pe; i1 = e; }
      }
      float den = v0 + v1 + 1e-9f;
      tok_e[t * 2]     = i0; tok_g[t * 2]     = v0 / den;
      tok_e[t * 2 + 1] = i1; tok_g[t * 2 + 1] = v1 / den;
      atomicAdd(&cnt[i0], 1);
      atomicAdd(&cnt[i1], 1);
    }
  }
}

// ---------------- padded segment offsets ----------------
__global__ void offsets_kernel(const int* __restrict__ cnt, int* __restrict__ seg) {
  if (threadIdx.x == 0 && blockIdx.x == 0) {
    int s = 0;
    for (int e = 0; e < NE; e++) { seg[e] = s; s += ((cnt[e] + TM - 1) / TM) * TM; }
    seg[NE] = s;
  }
}

// ---------------- scatter tokens into slot-major order ----------------
__global__ void route_kernel(const int* __restrict__ tok_e, const float* __restrict__ tok_g,
                             const int* __restrict__ seg, int* __restrict__ cnt2,
                             int* __restrict__ token_row, float* __restrict__ gate_row,
                             int* __restrict__ tok_pos) {
  int t = blockIdx.x * blockDim.x + threadIdx.x;
  if (t >= NTOK) return;
#pragma unroll
  for (int k = 0; k < 2; k++) {
    int e = tok_e[t * 2 + k];
    float g = tok_g[t * 2 + k];
    int pos = seg[e] + atomicAdd(&cnt2[e], 1);
    token_row[pos] = t;
    gate_row[pos] = g;
    tok_pos[t * 2 + k] = pos;
  }
}

// ---------------- GEMM1: h = gelu(x[slots] @ W1[e] + b1[e]) ----------------
__global__ __launch_bounds__(256)
void gemm1_kernel(const unsigned short* __restrict__ xb, const unsigned short* __restrict__ w1t,
                  const float* __restrict__ b1, const int* __restrict__ token_row,
                  const int* __restrict__ seg, const unsigned short* __restrict__ zbuf,
                  unsigned short* __restrict__ hbuf) {
  __shared__ __align__(16) unsigned short As[TM * TKK];
  __shared__ __align__(16) unsigned short Bs[TN * TKK];
  int row0 = blockIdx.y * TM;
  int total = seg[NE];
  if (row0 >= total) return;
  int e = 0;
  while (row0 >= seg[e + 1]) e++;
  int n0 = blockIdx.x * TN;
  int tid = threadIdx.x;
  int lane = tid & 63;
  int w = tid >> 6;
  int wm = tid >> 7;
  int wn = (tid >> 6) & 1;
  int lrow = lane >> 3;       // 0..7
  int lk   = (lane & 7) * 8;  // element offset within 64-elem row

  floatx4 zero4 = {0.f, 0.f, 0.f, 0.f};
  floatx4 acc[4][4];
#pragma unroll
  for (int a = 0; a < 4; a++)
#pragma unroll
    for (int b = 0; b < 4; b++) acc[a][b] = zero4;

  const unsigned short* w1e = w1t + (size_t)e * DIM * HID;
  const unsigned short* srcA[4];
  const unsigned short* srcB[4];
#pragma unroll
  for (int i = 0; i < 4; i++) {
    int r = w * 32 + i * 8 + lrow;
    int t = token_row[row0 + r];
    srcA[i] = (t >= 0 ? xb + (size_t)t * DIM : zbuf) + lk;
    srcB[i] = w1e + (size_t)(n0 + r) * DIM + lk;
  }

  int mr = lane & 15;
  int kq = (lane >> 4) * 8;

  for (int k0 = 0; k0 < DIM; k0 += TKK) {
#pragma unroll
    for (int i = 0; i < 4; i++) {
      async_ld16(srcA[i] + k0, &As[(w * 32 + i * 8 + lrow) * TKK + lk]);
      async_ld16(srcB[i] + k0, &Bs[(w * 32 + i * 8 + lrow) * TKK + lk]);
    }
    __syncthreads();
#pragma unroll
    for (int kk = 0; kk < TKK; kk += 32) {
      bf16x8 af[4], bfr[4];
#pragma unroll
      for (int im = 0; im < 4; im++)
        af[im] = *(const bf16x8*)&As[(wm * 64 + im * 16 + mr) * TKK + kk + kq];
#pragma unroll
      for (int in = 0; in < 4; in++)
        bfr[in] = *(const bf16x8*)&Bs[(wn * 64 + in * 16 + mr) * TKK + kk + kq];
#pragma unroll
      for (int im = 0; im < 4; im++)
#pragma unroll
        for (int in = 0; in < 4; in++)
          acc[im][in] = __builtin_amdgcn_mfma_f32_16x16x32_bf16(af[im], bfr[in], acc[im][in], 0, 0, 0);
    }
    __syncthreads();
  }
  int quad = lane >> 4;
  int c16 = lane & 15;
  const float* b1e = b1 + e * HID;
#pragma unroll
  for (int im = 0; im < 4; im++) {
    int rb = row0 + wm * 64 + im * 16 + quad * 4;
#pragma unroll
    for (int in = 0; in < 4; in++) {
      int c = n0 + wn * 64 + in * 16 + c16;
      float bias = b1e[c];
#pragma unroll
      for (int i = 0; i < 4; i++) {
        float v = acc[im][in][i] + bias;
        v = 0.5f * v * (1.0f + erff(v * 0.70710678118654752f));
        hbuf[(size_t)(rb + i) * HID + c] = f2bf(v);
      }
    }
  }
}

// ---------------- GEMM2: obuf[slot] = gate * (h @ W2[e] + b2[e]) ----------------
__global__ __launch_bounds__(256)
void gemm2_kernel(const unsigned short* __restrict__ hbuf, const unsigned short* __restrict__ w2t,
                  const float* __restrict__ b2, const float* __restrict__ gate_row,
                  const int* __restrict__ seg, unsigned short* __restrict__ obuf) {
  __shared__ __align__(16) unsigned short As[TM * TKK];
  __shared__ __align__(16) unsigned short Bs[TN * TKK];
  int row0 = blockIdx.y * TM;
  int total = seg[NE];
  if (row0 >= total) return;
  int e = 0;
  while (row0 >= seg[e + 1]) e++;
  int n0 = blockIdx.x * TN;
  int tid = threadIdx.x;
  int lane = tid & 63;
  int w = tid >> 6;
  int wm = tid >> 7;
  int wn = (tid >> 6) & 1;
  int lrow = lane >> 3;
  int lk   = (lane & 7) * 8;

  floatx4 zero4 = {0.f, 0.f, 0.f, 0.f};
  floatx4 acc[4][4];
#pragma unroll
  for (int a = 0; a < 4; a++)
#pragma unroll
    for (int b = 0; b < 4; b++) acc[a][b] = zero4;

  const unsigned short* w2e = w2t + (size_t)e * DIM * HID;
  const unsigned short* srcA[4];
  const unsigned short* srcB[4];
#pragma unroll
  for (int i = 0; i < 4; i++) {
    int r = w * 32 + i * 8 + lrow;
    srcA[i] = hbuf + (size_t)(row0 + r) * HID + lk;
    srcB[i] = w2e + (size_t)(n0 + r) * HID + lk;
  }

  int mr = lane & 15;
  int kq = (lane >> 4) * 8;

  for (int k0 = 0; k0 < HID; k0 += TKK) {
#pragma unroll
    for (int i = 0; i < 4; i++) {
      async_ld16(srcA[i] + k0, &As[(w * 32 + i * 8 + lrow) * TKK + lk]);
      async_ld16(srcB[i] + k0, &Bs[(w * 32 + i * 8 + lrow) * TKK + lk]);
    }
    __syncthreads();
#pragma unroll
    for (int kk = 0; kk < TKK; kk += 32) {
      bf16x8 af[4], bfr[4];
#pragma unroll
      for (int im = 0; im < 4; im++)
        af[im] = *(const bf16x8*)&As[(wm * 64 + im * 16 + mr) * TKK + kk + kq];
#pragma unroll
      for (int in = 0; in < 4; in++)
        bfr[in] = *(const bf16x8*)&Bs[(wn * 64 + in * 16 + mr) * TKK + kk + kq];
#pragma unroll
      for (int im = 0; im < 4; im++)
#pragma unroll
        for (int in = 0; in < 4; in++)
          acc[im][in] = __builtin_amdgcn_mfma_f32_16x16x32_bf16(af[im], bfr[in], acc[im][in], 0, 0, 0);
    }
    __syncthreads();
  }
  int quad = lane >> 4;
  int c16 = lane & 15;
  const float* b2e = b2 + e * DIM;
#pragma unroll
  for (int im = 0; im < 4; im++) {
    int rb = row0 + wm * 64 + im * 16 + quad * 4;
    float gs[4];
#pragma unroll
    for (int i = 0; i < 4; i++) gs[i] = gate_row[rb + i];
#pragma unroll
    for (int in = 0; in < 4; in++) {
      int c = n0 + wn * 64 + in * 16 + c16;
      float bias = b2e[c];
#pragma unroll
      for (int i = 0; i < 4; i++) {
        float val = gs[i] * (acc[im][in][i] + bias);
        obuf[(size_t)(rb + i) * DIM + c] = f2bf(val);
      }
    }
  }
}

// ---------------- combine: y[t] = obuf[pos0] + obuf[pos1] ----------------
__global__ void combine_kernel(const unsigned short* __restrict__ obuf,
                               const int* __restrict__ tok_pos,
                               float* __restrict__ y) {
  int idx = blockIdx.x * 256 + threadIdx.x;
  int t = idx >> 7;            // DIM/8 = 128 chunks per token
  int c = (idx & 127) << 3;
  int p0 = tok_pos[t * 2];
  int p1 = tok_pos[t * 2 + 1];
  uint4 a = *(const uint4*)(obuf + (size_t)p0 * DIM + c);
  uint4 b = *(const uint4*)(obuf + (size_t)p1 * DIM + c);
  float out[8];
  unsigned au[4] = {a.x, a.y, a.z, a.w};
  unsigned bu[4] = {b.x, b.y, b.z, b.w};
#pragma unroll
  for (int i = 0; i < 4; i++) {
    union { unsigned u; float f; } lo0, hi0, lo1, hi1;
    lo0.u = au[i] << 16; hi0.u = au[i] & 0xFFFF0000u;
    lo1.u = bu[i] << 16; hi1.u = bu[i] & 0xFFFF0000u;
    out[i * 2]     = lo0.f + lo1.f;
    out[i * 2 + 1] = hi0.f + hi1.f;
  }
  float* yp = y + (size_t)t * DIM + c;
  *(float4*)yp       = *(float4*)&out[0];
  *(float4*)(yp + 4) = *(float4*)&out[4];
}

// ---------------- launch ----------------
extern "C" void kernel_launch(void* const* d_in, const int* in_sizes, int n_in,
                              void* d_out, int out_size, void* d_ws, size_t ws_size,
                              hipStream_t stream) {
  const float* x  = (const float*)d_in[0];
  const float* Wg = (const float*)d_in[1];
  const float* bg = (const float*)d_in[2];
  const float* W1 = (const float*)d_in[3];
  const float* b1 = (const float*)d_in[4];
  const float* W2 = (const float*)d_in[5];
  const float* b2 = (const float*)d_in[6];
  float* y = (float*)d_out;
  char* ws = (char*)d_ws;

  constexpr size_t OFF_META = 0;                                  // cnt@0, cnt2@64, seg@128
  constexpr size_t OFF_TOKE = 256;
  constexpr size_t OFF_TOKG = OFF_TOKE + (size_t)NTOK * 2 * 4;
  constexpr size_t OFF_TPOS = OFF_TOKG + (size_t)NTOK * 2 * 4;
  constexpr size_t OFF_TROW = OFF_TPOS + (size_t)NTOK * 2 * 4;
  constexpr size_t OFF_GROW = OFF_TROW + (size_t)CAP * 4;
  constexpr size_t OFF_ZB   = OFF_GROW + (size_t)CAP * 4;
  constexpr size_t OFF_XB   = OFF_ZB  + (size_t)DIM * 2;
  constexpr size_t OFF_W1T  = OFF_XB  + (size_t)NTOK * DIM * 2;
  constexpr size_t OFF_W2T  = OFF_W1T + (size_t)NE * DIM * HID * 2;
  constexpr size_t OFF_H    = OFF_W2T + (size_t)NE * DIM * HID * 2;
  // obuf aliases xb+w1t (both dead before gemm2 runs): needs CAP*DIM*2 = 35.7MB < 50.2MB
  constexpr size_t OFF_OBUF = OFF_XB;

  int* cnt        = (int*)(ws + OFF_META);
  int* cnt2       = (int*)(ws + OFF_META + 64);
  int* seg        = (int*)(ws + OFF_META + 128);
  int* tok_e      = (int*)(ws + OFF_TOKE);
  float* tok_g    = (float*)(ws + OFF_TOKG);
  int* tok_pos    = (int*)(ws + OFF_TPOS);
  int* token_row  = (int*)(ws + OFF_TROW);
  float* gate_row = (float*)(ws + OFF_GROW);
  unsigned short* zbuf = (unsigned short*)(ws + OFF_ZB);
  unsigned short* xb   = (unsigned short*)(ws + OFF_XB);
  unsigned short* w1t  = (unsigned short*)(ws + OFF_W1T);
  unsigned short* w2t  = (unsigned short*)(ws + OFF_W2T);
  unsigned short* hbuf = (unsigned short*)(ws + OFF_H);
  unsigned short* obuf = (unsigned short*)(ws + OFF_OBUF);

  hipMemsetAsync(ws, 0, 192, stream);                       // cnt, cnt2
  hipMemsetAsync(token_row, 0xFF, (size_t)CAP * 4, stream); // token_row = -1
  hipMemsetAsync(zbuf, 0, (size_t)DIM * 2, stream);         // zero row for padding slots

  transpose_cast_kernel<<<dim3(HID / 64, DIM / 64, NE), 256, 0, stream>>>(W1, w1t, DIM, HID);
  transpose_cast_kernel<<<dim3(DIM / 64, HID / 64, NE), 256, 0, stream>>>(W2, w2t, HID, DIM);
  gating_kernel<<<NTOK / 8, 256, 0, stream>>>(x, Wg, bg, tok_e, tok_g, cnt, xb);
  offsets_kernel<<<1, 64, 0, stream>>>(cnt, seg);
  route_kernel<<<NTOK / 256, 256, 0, stream>>>(tok_e, tok_g, seg, cnt2, token_row, gate_row, tok_pos);
  gemm1_kernel<<<dim3(HID / TN, CAP / TM), 256, 0, stream>>>(xb, w1t, b1, token_row, seg, zbuf, hbuf);
  gemm2_kernel<<<dim3(DIM / TN, CAP / TM), 256, 0, stream>>>(hbuf, w2t, b2, gate_row, seg, obuf);
  combine_kernel<<<NTOK * DIM / 8 / 256, 256, 0, stream>>>(obuf, tok_pos, y);
}

// Round 4
// 499.926 us; speedup vs baseline: 1.6467x; 1.4780x over previous
//
#include <hip/hip_runtime.h>
#include <stdint.h>

#define NTOK 8192
#define DIM  1024
#define HID  2048
#define NE   8
#define CAP  17408   // 16384 slots + 8*128 max padding
#define TM 128
#define TN 128
#define TKK 64       // k elems per tile; row = 128 B (unpadded, required by global_load_lds)

typedef __bf16  bf16x8  __attribute__((ext_vector_type(8)));
typedef float   floatx4 __attribute__((ext_vector_type(4)));

__device__ __forceinline__ unsigned short f2bf(float f) {
  union { float f; unsigned u; } v; v.f = f;
  unsigned r = v.u + 0x7FFFu + ((v.u >> 16) & 1u);
  return (unsigned short)(r >> 16);
}

__device__ __forceinline__ void async_ld16(const unsigned short* g, unsigned short* l) {
  __builtin_amdgcn_global_load_lds(
      (const __attribute__((address_space(1))) unsigned int*)(const void*)g,
      (__attribute__((address_space(3))) unsigned int*)(void*)l, 16, 0, 0);
}

// ------- transpose + cast: src[e][R][C] fp32 -> dst[e][C][R] bf16 -------
__global__ void transpose_cast_kernel(const float* __restrict__ src,
                                      unsigned short* __restrict__ dst,
                                      int R, int C) {
  __shared__ unsigned short T[64][65];
  int e = blockIdx.z;
  const float* S = src + (size_t)e * R * C;
  unsigned short* D2 = dst + (size_t)e * R * C;
  int c0 = blockIdx.x * 64;
  int r0 = blockIdx.y * 64;
  int col = threadIdx.x & 63;
  int rr  = threadIdx.x >> 6;
#pragma unroll
  for (int i = 0; i < 16; i++) {
    int r = rr + i * 4;
    T[col][r] = f2bf(S[(size_t)(r0 + r) * C + c0 + col]);
  }
  __syncthreads();
#pragma unroll
  for (int i = 0; i < 16; i++) {
    int r = rr + i * 4;
    D2[(size_t)(c0 + r) * R + r0 + col] = T[r][col];
  }
}

// ------- gating: LDS-staged transposed Wg, fused x->bf16 cast, NO atomics -------
__global__ __launch_bounds__(256)
void gating_kernel(const float* __restrict__ x, const float* __restrict__ Wg,
                   const float* __restrict__ bg, int* __restrict__ tok_e,
                   float* __restrict__ tok_g, unsigned short* __restrict__ xb) {
  __shared__ float WgS[NE * DIM];   // transposed [e][d], 32 KB
  int tid = threadIdx.x;
#pragma unroll
  for (int j = 0; j < NE * DIM / 256; j++) {
    int i = j * 256 + tid;
    WgS[(i & 7) * DIM + (i >> 3)] = Wg[i];     // Wg is [d][e] row-major
  }
  __syncthreads();
  int wave = tid >> 6;
  int lane = tid & 63;
#pragma unroll
  for (int ti = 0; ti < 2; ti++) {
    int t = blockIdx.x * 8 + wave * 2 + ti;
    const float* xr = x + (size_t)t * DIM;
    float p[NE];
#pragma unroll
    for (int e = 0; e < NE; e++) p[e] = 0.f;
#pragma unroll
    for (int it = 0; it < DIM / 256; it++) {
      int d = (it * 64 + lane) * 4;
      float4 xv = *(const float4*)&xr[d];
      uint2 o;
      o.x = (unsigned)f2bf(xv.x) | ((unsigned)f2bf(xv.y) << 16);
      o.y = (unsigned)f2bf(xv.z) | ((unsigned)f2bf(xv.w) << 16);
      *(uint2*)&xb[(size_t)t * DIM + d] = o;
#pragma unroll
      for (int e = 0; e < NE; e++) {
        float4 wv = *(const float4*)&WgS[e * DIM + d];
        p[e] += xv.x * wv.x + xv.y * wv.y + xv.z * wv.z + xv.w * wv.w;
      }
    }
#pragma unroll
    for (int e = 0; e < NE; e++) {
#pragma unroll
      for (int off = 32; off > 0; off >>= 1) p[e] += __shfl_xor(p[e], off);
    }
    if (lane == 0) {
      float s[NE];
      float m = -1e30f;
#pragma unroll
      for (int e = 0; e < NE; e++) { s[e] = (p[e] + bg[e]) * 0.2f; m = fmaxf(m, s[e]); }
      float sum = 0.f;
#pragma unroll
      for (int e = 0; e < NE; e++) { s[e] = expf(s[e] - m); sum += s[e]; }
      float inv = 1.0f / sum;
      int i0 = 0; float v0 = -1.f;
#pragma unroll
      for (int e = 0; e < NE; e++) { float pe = s[e] * inv; if (pe > v0) { v0 = pe; i0 = e; } }
      int i1 = -1; float v1 = -1.f;
#pragma unroll
      for (int e = 0; e < NE; e++) {
        if (e == i0) continue;
        float pe = s[e] * inv; if (pe > v1) { v1 = pe; i1 = e; }
      }
      float den = v0 + v1 + 1e-9f;
      tok_e[t * 2]     = i0; tok_g[t * 2]     = v0 / den;
      tok_e[t * 2 + 1] = i1; tok_g[t * 2 + 1] = v1 / den;
    }
  }
}

// ------- count: LDS histogram, 8 global atomics per block (32 blocks) -------
__global__ __launch_bounds__(256)
void count_kernel(const int* __restrict__ tok_e, int* __restrict__ cnt) {
  __shared__ int hist[NE];
  int tid = threadIdx.x;
  if (tid < NE) hist[tid] = 0;
  __syncthreads();
  int i0 = blockIdx.x * 512 + tid;
  atomicAdd(&hist[tok_e[i0]], 1);
  atomicAdd(&hist[tok_e[i0 + 256]], 1);
  __syncthreads();
  if (tid < NE) atomicAdd(&cnt[tid], hist[tid]);
}

// ---------------- padded segment offsets ----------------
__global__ void offsets_kernel(const int* __restrict__ cnt, int* __restrict__ seg) {
  if (threadIdx.x == 0 && blockIdx.x == 0) {
    int s = 0;
    for (int e = 0; e < NE; e++) { seg[e] = s; s += ((cnt[e] + TM - 1) / TM) * TM; }
    seg[NE] = s;
  }
}

// ------- route v2: block-local ranks via LDS atomics, one range-reserve
//         global atomic per expert per block (32 blocks) -------
__global__ __launch_bounds__(256)
void route_kernel(const int* __restrict__ tok_e, const float* __restrict__ tok_g,
                  const int* __restrict__ seg, int* __restrict__ cnt2,
                  int* __restrict__ token_row, float* __restrict__ gate_row,
                  int* __restrict__ tok_pos) {
  __shared__ int hist[NE];
  __shared__ int base[NE];
  int tid = threadIdx.x;
  if (tid < NE) hist[tid] = 0;
  __syncthreads();
  int t = blockIdx.x * 256 + tid;
  int e0 = tok_e[t * 2];
  int e1 = tok_e[t * 2 + 1];
  int r0 = atomicAdd(&hist[e0], 1);   // local rank within block
  int r1 = atomicAdd(&hist[e1], 1);
  __syncthreads();
  if (tid < NE) base[tid] = atomicAdd(&cnt2[tid], hist[tid]);  // reserve range
  __syncthreads();
  int p0 = seg[e0] + base[e0] + r0;
  int p1 = seg[e1] + base[e1] + r1;
  token_row[p0] = t; gate_row[p0] = tok_g[t * 2];     tok_pos[t * 2]     = p0;
  token_row[p1] = t; gate_row[p1] = tok_g[t * 2 + 1]; tok_pos[t * 2 + 1] = p1;
}

// ---------------- GEMM1: h = gelu(x[slots] @ W1[e] + b1[e]) ----------------
__global__ __launch_bounds__(256)
void gemm1_kernel(const unsigned short* __restrict__ xb, const unsigned short* __restrict__ w1t,
                  const float* __restrict__ b1, const int* __restrict__ token_row,
                  const int* __restrict__ seg, const unsigned short* __restrict__ zbuf,
                  unsigned short* __restrict__ hbuf) {
  __shared__ __align__(16) unsigned short As[TM * TKK];
  __shared__ __align__(16) unsigned short Bs[TN * TKK];
  int row0 = blockIdx.y * TM;
  int total = seg[NE];
  if (row0 >= total) return;
  int e = 0;
  while (row0 >= seg[e + 1]) e++;
  int n0 = blockIdx.x * TN;
  int tid = threadIdx.x;
  int lane = tid & 63;
  int w = tid >> 6;
  int wm = tid >> 7;
  int wn = (tid >> 6) & 1;
  int lrow = lane >> 3;       // 0..7
  int lk   = (lane & 7) * 8;  // element offset within 64-elem row

  floatx4 zero4 = {0.f, 0.f, 0.f, 0.f};
  floatx4 acc[4][4];
#pragma unroll
  for (int a = 0; a < 4; a++)
#pragma unroll
    for (int b = 0; b < 4; b++) acc[a][b] = zero4;

  const unsigned short* w1e = w1t + (size_t)e * DIM * HID;
  const unsigned short* srcA[4];
  const unsigned short* srcB[4];
#pragma unroll
  for (int i = 0; i < 4; i++) {
    int r = w * 32 + i * 8 + lrow;
    int t = token_row[row0 + r];
    srcA[i] = (t >= 0 ? xb + (size_t)t * DIM : zbuf) + lk;
    srcB[i] = w1e + (size_t)(n0 + r) * DIM + lk;
  }

  int mr = lane & 15;
  int kq = (lane >> 4) * 8;

  for (int k0 = 0; k0 < DIM; k0 += TKK) {
#pragma unroll
    for (int i = 0; i < 4; i++) {
      async_ld16(srcA[i] + k0, &As[(w * 32 + i * 8 + lrow) * TKK + lk]);
      async_ld16(srcB[i] + k0, &Bs[(w * 32 + i * 8 + lrow) * TKK + lk]);
    }
    __syncthreads();
#pragma unroll
    for (int kk = 0; kk < TKK; kk += 32) {
      bf16x8 af[4], bfr[4];
#pragma unroll
      for (int im = 0; im < 4; im++)
        af[im] = *(const bf16x8*)&As[(wm * 64 + im * 16 + mr) * TKK + kk + kq];
#pragma unroll
      for (int in = 0; in < 4; in++)
        bfr[in] = *(const bf16x8*)&Bs[(wn * 64 + in * 16 + mr) * TKK + kk + kq];
#pragma unroll
      for (int im = 0; im < 4; im++)
#pragma unroll
        for (int in = 0; in < 4; in++)
          acc[im][in] = __builtin_amdgcn_mfma_f32_16x16x32_bf16(af[im], bfr[in], acc[im][in], 0, 0, 0);
    }
    __syncthreads();
  }
  int quad = lane >> 4;
  int c16 = lane & 15;
  const float* b1e = b1 + e * HID;
#pragma unroll
  for (int im = 0; im < 4; im++) {
    int rb = row0 + wm * 64 + im * 16 + quad * 4;
#pragma unroll
    for (int in = 0; in < 4; in++) {
      int c = n0 + wn * 64 + in * 16 + c16;
      float bias = b1e[c];
#pragma unroll
      for (int i = 0; i < 4; i++) {
        float v = acc[im][in][i] + bias;
        v = 0.5f * v * (1.0f + erff(v * 0.70710678118654752f));
        hbuf[(size_t)(rb + i) * HID + c] = f2bf(v);
      }
    }
  }
}

// ---------------- GEMM2: obuf[slot] = gate * (h @ W2[e] + b2[e]) ----------------
__global__ __launch_bounds__(256)
void gemm2_kernel(const unsigned short* __restrict__ hbuf, const unsigned short* __restrict__ w2t,
                  const float* __restrict__ b2, const float* __restrict__ gate_row,
                  const int* __restrict__ seg, unsigned short* __restrict__ obuf) {
  __shared__ __align__(16) unsigned short As[TM * TKK];
  __shared__ __align__(16) unsigned short Bs[TN * TKK];
  int row0 = blockIdx.y * TM;
  int total = seg[NE];
  if (row0 >= total) return;
  int e = 0;
  while (row0 >= seg[e + 1]) e++;
  int n0 = blockIdx.x * TN;
  int tid = threadIdx.x;
  int lane = tid & 63;
  int w = tid >> 6;
  int wm = tid >> 7;
  int wn = (tid >> 6) & 1;
  int lrow = lane >> 3;
  int lk   = (lane & 7) * 8;

  floatx4 zero4 = {0.f, 0.f, 0.f, 0.f};
  floatx4 acc[4][4];
#pragma unroll
  for (int a = 0; a < 4; a++)
#pragma unroll
    for (int b = 0; b < 4; b++) acc[a][b] = zero4;

  const unsigned short* w2e = w2t + (size_t)e * DIM * HID;
  const unsigned short* srcA[4];
  const unsigned short* srcB[4];
#pragma unroll
  for (int i = 0; i < 4; i++) {
    int r = w * 32 + i * 8 + lrow;
    srcA[i] = hbuf + (size_t)(row0 + r) * HID + lk;
    srcB[i] = w2e + (size_t)(n0 + r) * HID + lk;
  }

  int mr = lane & 15;
  int kq = (lane >> 4) * 8;

  for (int k0 = 0; k0 < HID; k0 += TKK) {
#pragma unroll
    for (int i = 0; i < 4; i++) {
      async_ld16(srcA[i] + k0, &As[(w * 32 + i * 8 + lrow) * TKK + lk]);
      async_ld16(srcB[i] + k0, &Bs[(w * 32 + i * 8 + lrow) * TKK + lk]);
    }
    __syncthreads();
#pragma unroll
    for (int kk = 0; kk < TKK; kk += 32) {
      bf16x8 af[4], bfr[4];
#pragma unroll
      for (int im = 0; im < 4; im++)
        af[im] = *(const bf16x8*)&As[(wm * 64 + im * 16 + mr) * TKK + kk + kq];
#pragma unroll
      for (int in = 0; in < 4; in++)
        bfr[in] = *(const bf16x8*)&Bs[(wn * 64 + in * 16 + mr) * TKK + kk + kq];
#pragma unroll
      for (int im = 0; im < 4; im++)
#pragma unroll
        for (int in = 0; in < 4; in++)
          acc[im][in] = __builtin_amdgcn_mfma_f32_16x16x32_bf16(af[im], bfr[in], acc[im][in], 0, 0, 0);
    }
    __syncthreads();
  }
  int quad = lane >> 4;
  int c16 = lane & 15;
  const float* b2e = b2 + e * DIM;
#pragma unroll
  for (int im = 0; im < 4; im++) {
    int rb = row0 + wm * 64 + im * 16 + quad * 4;
    float gs[4];
#pragma unroll
    for (int i = 0; i < 4; i++) gs[i] = gate_row[rb + i];
#pragma unroll
    for (int in = 0; in < 4; in++) {
      int c = n0 + wn * 64 + in * 16 + c16;
      float bias = b2e[c];
#pragma unroll
      for (int i = 0; i < 4; i++) {
        float val = gs[i] * (acc[im][in][i] + bias);
        obuf[(size_t)(rb + i) * DIM + c] = f2bf(val);
      }
    }
  }
}

// ---------------- combine: y[t] = obuf[pos0] + obuf[pos1] ----------------
__global__ void combine_kernel(const unsigned short* __restrict__ obuf,
                               const int* __restrict__ tok_pos,
                               float* __restrict__ y) {
  int idx = blockIdx.x * 256 + threadIdx.x;
  int t = idx >> 7;            // DIM/8 = 128 chunks per token
  int c = (idx & 127) << 3;
  int p0 = tok_pos[t * 2];
  int p1 = tok_pos[t * 2 + 1];
  uint4 a = *(const uint4*)(obuf + (size_t)p0 * DIM + c);
  uint4 b = *(const uint4*)(obuf + (size_t)p1 * DIM + c);
  float out[8];
  unsigned au[4] = {a.x, a.y, a.z, a.w};
  unsigned bu[4] = {b.x, b.y, b.z, b.w};
#pragma unroll
  for (int i = 0; i < 4; i++) {
    union { unsigned u; float f; } lo0, hi0, lo1, hi1;
    lo0.u = au[i] << 16; hi0.u = au[i] & 0xFFFF0000u;
    lo1.u = bu[i] << 16; hi1.u = bu[i] & 0xFFFF0000u;
    out[i * 2]     = lo0.f + lo1.f;
    out[i * 2 + 1] = hi0.f + hi1.f;
  }
  float* yp = y + (size_t)t * DIM + c;
  *(float4*)yp       = *(float4*)&out[0];
  *(float4*)(yp + 4) = *(float4*)&out[4];
}

// ---------------- launch ----------------
extern "C" void kernel_launch(void* const* d_in, const int* in_sizes, int n_in,
                              void* d_out, int out_size, void* d_ws, size_t ws_size,
                              hipStream_t stream) {
  const float* x  = (const float*)d_in[0];
  const float* Wg = (const float*)d_in[1];
  const float* bg = (const float*)d_in[2];
  const float* W1 = (const float*)d_in[3];
  const float* b1 = (const float*)d_in[4];
  const float* W2 = (const float*)d_in[5];
  const float* b2 = (const float*)d_in[6];
  float* y = (float*)d_out;
  char* ws = (char*)d_ws;

  constexpr size_t OFF_META = 0;                                  // cnt@0, cnt2@64, seg@128
  constexpr size_t OFF_TOKE = 256;
  constexpr size_t OFF_TOKG = OFF_TOKE + (size_t)NTOK * 2 * 4;
  constexpr size_t OFF_TPOS = OFF_TOKG + (size_t)NTOK * 2 * 4;
  constexpr size_t OFF_TROW = OFF_TPOS + (size_t)NTOK * 2 * 4;
  constexpr size_t OFF_GROW = OFF_TROW + (size_t)CAP * 4;
  constexpr size_t OFF_ZB   = OFF_GROW + (size_t)CAP * 4;
  constexpr size_t OFF_XB   = OFF_ZB  + (size_t)DIM * 2;
  constexpr size_t OFF_W1T  = OFF_XB  + (size_t)NTOK * DIM * 2;
  constexpr size_t OFF_W2T  = OFF_W1T + (size_t)NE * DIM * HID * 2;
  constexpr size_t OFF_H    = OFF_W2T + (size_t)NE * DIM * HID * 2;
  // obuf aliases xb+w1t (both dead before gemm2 runs): needs CAP*DIM*2 = 35.7MB < 50.2MB
  constexpr size_t OFF_OBUF = OFF_XB;

  int* cnt        = (int*)(ws + OFF_META);
  int* cnt2       = (int*)(ws + OFF_META + 64);
  int* seg        = (int*)(ws + OFF_META + 128);
  int* tok_e      = (int*)(ws + OFF_TOKE);
  float* tok_g    = (float*)(ws + OFF_TOKG);
  int* tok_pos    = (int*)(ws + OFF_TPOS);
  int* token_row  = (int*)(ws + OFF_TROW);
  float* gate_row = (float*)(ws + OFF_GROW);
  unsigned short* zbuf = (unsigned short*)(ws + OFF_ZB);
  unsigned short* xb   = (unsigned short*)(ws + OFF_XB);
  unsigned short* w1t  = (unsigned short*)(ws + OFF_W1T);
  unsigned short* w2t  = (unsigned short*)(ws + OFF_W2T);
  unsigned short* hbuf = (unsigned short*)(ws + OFF_H);
  unsigned short* obuf = (unsigned short*)(ws + OFF_OBUF);

  hipMemsetAsync(ws, 0, 192, stream);                       // cnt, cnt2
  hipMemsetAsync(token_row, 0xFF, (size_t)CAP * 4, stream); // token_row = -1
  hipMemsetAsync(zbuf, 0, (size_t)DIM * 2, stream);         // zero row for padding slots

  transpose_cast_kernel<<<dim3(HID / 64, DIM / 64, NE), 256, 0, stream>>>(W1, w1t, DIM, HID);
  transpose_cast_kernel<<<dim3(DIM / 64, HID / 64, NE), 256, 0, stream>>>(W2, w2t, HID, DIM);
  gating_kernel<<<NTOK / 8, 256, 0, stream>>>(x, Wg, bg, tok_e, tok_g, xb);
  count_kernel<<<NTOK * 2 / 512, 256, 0, stream>>>(tok_e, cnt);
  offsets_kernel<<<1, 64, 0, stream>>>(cnt, seg);
  route_kernel<<<NTOK / 256, 256, 0, stream>>>(tok_e, tok_g, seg, cnt2, token_row, gate_row, tok_pos);
  gemm1_kernel<<<dim3(HID / TN, CAP / TM), 256, 0, stream>>>(xb, w1t, b1, token_row, seg, zbuf, hbuf);
  gemm2_kernel<<<dim3(DIM / TN, CAP / TM), 256, 0, stream>>>(hbuf, w2t, b2, gate_row, seg, obuf);
  combine_kernel<<<NTOK * DIM / 8 / 256, 256, 0, stream>>>(obuf, tok_pos, y);
}

// Round 5
// 477.399 us; speedup vs baseline: 1.7244x; 1.0472x over previous
//
#include <hip/hip_runtime.h>
#include <stdint.h>

#define NTOK 8192
#define DIM  1024
#define HID  2048
#define NE   8
#define CAP  17408   // 16384 slots + 8*128 max padding
#define TM 128
#define TN 256
#define TKK 64       // k elems per tile; row = 128 B (unpadded, required by global_load_lds)

typedef __bf16  bf16x8  __attribute__((ext_vector_type(8)));
typedef float   floatx4 __attribute__((ext_vector_type(4)));

__device__ __forceinline__ unsigned short f2bf(float f) {
  union { float f; unsigned u; } v; v.f = f;
  unsigned r = v.u + 0x7FFFu + ((v.u >> 16) & 1u);
  return (unsigned short)(r >> 16);
}

__device__ __forceinline__ void async_ld16(const unsigned short* g, unsigned short* l) {
  __builtin_amdgcn_global_load_lds(
      (const __attribute__((address_space(1))) unsigned int*)(const void*)g,
      (__attribute__((address_space(3))) unsigned int*)(void*)l, 16, 0, 0);
}

// fast GELU (tanh approx): x * sigmoid(2*0.7978845608*(x+0.044715 x^3))
__device__ __forceinline__ float gelu_fast(float v) {
  float g = 0.79788456080286536f * (v + 0.044715f * v * v * v);
  // sigmoid(2g) = 1/(1+exp2(-2g*log2e))
  float t = __builtin_amdgcn_exp2f(-2.8853900817779268f * g);
  return v * __builtin_amdgcn_rcpf(1.0f + t);
}

// pack 4 floats -> 4 bf16 in uint2
__device__ __forceinline__ uint2 pack4bf(float a, float b, float c, float d) {
  uint2 o;
  o.x = (unsigned)f2bf(a) | ((unsigned)f2bf(b) << 16);
  o.y = (unsigned)f2bf(c) | ((unsigned)f2bf(d) << 16);
  return o;
}

// ------- transpose + cast: src[e][R][C] fp32 -> dst[e][C][R] bf16 -------
__global__ void transpose_cast_kernel(const float* __restrict__ src,
                                      unsigned short* __restrict__ dst,
                                      int R, int C) {
  __shared__ unsigned short T[64][65];
  int e = blockIdx.z;
  const float* S = src + (size_t)e * R * C;
  unsigned short* D2 = dst + (size_t)e * R * C;
  int c0 = blockIdx.x * 64;
  int r0 = blockIdx.y * 64;
  int col = threadIdx.x & 63;
  int rr  = threadIdx.x >> 6;
#pragma unroll
  for (int i = 0; i < 16; i++) {
    int r = rr + i * 4;
    T[col][r] = f2bf(S[(size_t)(r0 + r) * C + c0 + col]);
  }
  __syncthreads();
#pragma unroll
  for (int i = 0; i < 16; i++) {
    int r = rr + i * 4;
    D2[(size_t)(c0 + r) * R + r0 + col] = T[r][col];
  }
}

// ------- gating: LDS-staged transposed Wg, fused x->bf16 cast, NO atomics -------
__global__ __launch_bounds__(256)
void gating_kernel(const float* __restrict__ x, const float* __restrict__ Wg,
                   const float* __restrict__ bg, int* __restrict__ tok_e,
                   float* __restrict__ tok_g, unsigned short* __restrict__ xb) {
  __shared__ float WgS[NE * DIM];   // transposed [e][d], 32 KB
  int tid = threadIdx.x;
#pragma unroll
  for (int j = 0; j < NE * DIM / 256; j++) {
    int i = j * 256 + tid;
    WgS[(i & 7) * DIM + (i >> 3)] = Wg[i];     // Wg is [d][e] row-major
  }
  __syncthreads();
  int wave = tid >> 6;
  int lane = tid & 63;
#pragma unroll
  for (int ti = 0; ti < 2; ti++) {
    int t = blockIdx.x * 8 + wave * 2 + ti;
    const float* xr = x + (size_t)t * DIM;
    float p[NE];
#pragma unroll
    for (int e = 0; e < NE; e++) p[e] = 0.f;
#pragma unroll
    for (int it = 0; it < DIM / 256; it++) {
      int d = (it * 64 + lane) * 4;
      float4 xv = *(const float4*)&xr[d];
      *(uint2*)&xb[(size_t)t * DIM + d] = pack4bf(xv.x, xv.y, xv.z, xv.w);
#pragma unroll
      for (int e = 0; e < NE; e++) {
        float4 wv = *(const float4*)&WgS[e * DIM + d];
        p[e] += xv.x * wv.x + xv.y * wv.y + xv.z * wv.z + xv.w * wv.w;
      }
    }
#pragma unroll
    for (int e = 0; e < NE; e++) {
#pragma unroll
      for (int off = 32; off > 0; off >>= 1) p[e] += __shfl_xor(p[e], off);
    }
    if (lane == 0) {
      float s[NE];
      float m = -1e30f;
#pragma unroll
      for (int e = 0; e < NE; e++) { s[e] = (p[e] + bg[e]) * 0.2f; m = fmaxf(m, s[e]); }
      float sum = 0.f;
#pragma unroll
      for (int e = 0; e < NE; e++) { s[e] = expf(s[e] - m); sum += s[e]; }
      float inv = 1.0f / sum;
      int i0 = 0; float v0 = -1.f;
#pragma unroll
      for (int e = 0; e < NE; e++) { float pe = s[e] * inv; if (pe > v0) { v0 = pe; i0 = e; } }
      int i1 = -1; float v1 = -1.f;
#pragma unroll
      for (int e = 0; e < NE; e++) {
        if (e == i0) continue;
        float pe = s[e] * inv; if (pe > v1) { v1 = pe; i1 = e; }
      }
      float den = v0 + v1 + 1e-9f;
      tok_e[t * 2]     = i0; tok_g[t * 2]     = v0 / den;
      tok_e[t * 2 + 1] = i1; tok_g[t * 2 + 1] = v1 / den;
    }
  }
}

// ------- count: LDS histogram, 8 global atomics per block (32 blocks) -------
__global__ __launch_bounds__(256)
void count_kernel(const int* __restrict__ tok_e, int* __restrict__ cnt) {
  __shared__ int hist[NE];
  int tid = threadIdx.x;
  if (tid < NE) hist[tid] = 0;
  __syncthreads();
  int i0 = blockIdx.x * 512 + tid;
  atomicAdd(&hist[tok_e[i0]], 1);
  atomicAdd(&hist[tok_e[i0 + 256]], 1);
  __syncthreads();
  if (tid < NE) atomicAdd(&cnt[tid], hist[tid]);
}

// ---------------- padded segment offsets ----------------
__global__ void offsets_kernel(const int* __restrict__ cnt, int* __restrict__ seg) {
  if (threadIdx.x == 0 && blockIdx.x == 0) {
    int s = 0;
    for (int e = 0; e < NE; e++) { seg[e] = s; s += ((cnt[e] + TM - 1) / TM) * TM; }
    seg[NE] = s;
  }
}

// ------- route: block-local ranks via LDS atomics, range-reserve per block -------
__global__ __launch_bounds__(256)
void route_kernel(const int* __restrict__ tok_e, const float* __restrict__ tok_g,
                  const int* __restrict__ seg, int* __restrict__ cnt2,
                  int* __restrict__ token_row, float* __restrict__ gate_row,
                  int* __restrict__ tok_pos) {
  __shared__ int hist[NE];
  __shared__ int base[NE];
  int tid = threadIdx.x;
  if (tid < NE) hist[tid] = 0;
  __syncthreads();
  int t = blockIdx.x * 256 + tid;
  int e0 = tok_e[t * 2];
  int e1 = tok_e[t * 2 + 1];
  int r0 = atomicAdd(&hist[e0], 1);   // local rank within block
  int r1 = atomicAdd(&hist[e1], 1);
  __syncthreads();
  if (tid < NE) base[tid] = atomicAdd(&cnt2[tid], hist[tid]);  // reserve range
  __syncthreads();
  int p0 = seg[e0] + base[e0] + r0;
  int p1 = seg[e1] + base[e1] + r1;
  token_row[p0] = t; gate_row[p0] = tok_g[t * 2];     tok_pos[t * 2]     = p0;
  token_row[p1] = t; gate_row[p1] = tok_g[t * 2 + 1]; tok_pos[t * 2 + 1] = p1;
}

// ---------------- GEMM1: h = gelu(x[slots] @ W1[e] + b1[e]), 128x256 tile ----------------
__global__ __launch_bounds__(256, 2)
void gemm1_kernel(const unsigned short* __restrict__ xb, const unsigned short* __restrict__ w1t,
                  const float* __restrict__ b1, const int* __restrict__ token_row,
                  const int* __restrict__ seg, const unsigned short* __restrict__ zbuf,
                  unsigned short* __restrict__ hbuf) {
  __shared__ __align__(16) unsigned short As[TM * TKK];   // 16 KB
  __shared__ __align__(16) unsigned short Bs[TN * TKK];   // 32 KB
  int row0 = blockIdx.y * TM;
  int total = seg[NE];
  if (row0 >= total) return;
  int e = 0;
  while (row0 >= seg[e + 1]) e++;
  int n0 = blockIdx.x * TN;
  int tid = threadIdx.x;
  int lane = tid & 63;
  int w = tid >> 6;
  int wm = tid >> 7;            // 0..1 (row half)
  int wn = (tid >> 6) & 1;      // 0..1 (col half)
  int lrow = lane >> 3;         // 0..7
  int lk   = (lane & 7) * 8;    // element offset within 64-elem row

  floatx4 zero4 = {0.f, 0.f, 0.f, 0.f};
  floatx4 acc[4][8];
#pragma unroll
  for (int a = 0; a < 4; a++)
#pragma unroll
    for (int b = 0; b < 8; b++) acc[a][b] = zero4;

  const unsigned short* w1e = w1t + (size_t)e * DIM * HID;
  const unsigned short* srcA[4];
  const unsigned short* srcB[8];
#pragma unroll
  for (int i = 0; i < 4; i++) {
    int r = w * 32 + i * 8 + lrow;
    int t = token_row[row0 + r];
    srcA[i] = (t >= 0 ? xb + (size_t)t * DIM : zbuf) + lk;
  }
#pragma unroll
  for (int i = 0; i < 8; i++) {
    int r = w * 64 + i * 8 + lrow;
    srcB[i] = w1e + (size_t)(n0 + r) * DIM + lk;
  }

  int mr = lane & 15;
  int kq = (lane >> 4) * 8;

  for (int k0 = 0; k0 < DIM; k0 += TKK) {
#pragma unroll
    for (int i = 0; i < 4; i++)
      async_ld16(srcA[i] + k0, &As[(w * 32 + i * 8 + lrow) * TKK + lk]);
#pragma unroll
    for (int i = 0; i < 8; i++)
      async_ld16(srcB[i] + k0, &Bs[(w * 64 + i * 8 + lrow) * TKK + lk]);
    __syncthreads();
#pragma unroll
    for (int kk = 0; kk < TKK; kk += 32) {
      bf16x8 af[4], bfr[8];
#pragma unroll
      for (int im = 0; im < 4; im++)
        af[im] = *(const bf16x8*)&As[(wm * 64 + im * 16 + mr) * TKK + kk + kq];
#pragma unroll
      for (int in = 0; in < 8; in++)
        bfr[in] = *(const bf16x8*)&Bs[(wn * 128 + in * 16 + mr) * TKK + kk + kq];
      // operand-swapped: D[col n'][row m'] so each lane owns 4 consecutive cols
#pragma unroll
      for (int im = 0; im < 4; im++)
#pragma unroll
        for (int in = 0; in < 8; in++)
          acc[im][in] = __builtin_amdgcn_mfma_f32_16x16x32_bf16(bfr[in], af[im], acc[im][in], 0, 0, 0);
    }
    __syncthreads();
  }
  // epilogue: lane owns row (lane&15 within im-group), 4 consecutive cols (quad*4)
  int quad = lane >> 4;
  int c16 = lane & 15;
  const float* b1e = b1 + e * HID;
#pragma unroll
  for (int im = 0; im < 4; im++) {
    int r = row0 + wm * 64 + im * 16 + c16;
#pragma unroll
    for (int in = 0; in < 8; in++) {
      int c = n0 + wn * 128 + in * 16 + quad * 4;
      float4 bias = *(const float4*)&b1e[c];
      float v0 = gelu_fast(acc[im][in][0] + bias.x);
      float v1 = gelu_fast(acc[im][in][1] + bias.y);
      float v2 = gelu_fast(acc[im][in][2] + bias.z);
      float v3 = gelu_fast(acc[im][in][3] + bias.w);
      *(uint2*)&hbuf[(size_t)r * HID + c] = pack4bf(v0, v1, v2, v3);
    }
  }
}

// ---------------- GEMM2: obuf[slot] = gate * (h @ W2[e] + b2[e]), 128x256 tile ----------------
__global__ __launch_bounds__(256, 2)
void gemm2_kernel(const unsigned short* __restrict__ hbuf, const unsigned short* __restrict__ w2t,
                  const float* __restrict__ b2, const float* __restrict__ gate_row,
                  const int* __restrict__ seg, unsigned short* __restrict__ obuf) {
  __shared__ __align__(16) unsigned short As[TM * TKK];
  __shared__ __align__(16) unsigned short Bs[TN * TKK];
  int row0 = blockIdx.y * TM;
  int total = seg[NE];
  if (row0 >= total) return;
  int e = 0;
  while (row0 >= seg[e + 1]) e++;
  int n0 = blockIdx.x * TN;
  int tid = threadIdx.x;
  int lane = tid & 63;
  int w = tid >> 6;
  int wm = tid >> 7;
  int wn = (tid >> 6) & 1;
  int lrow = lane >> 3;
  int lk   = (lane & 7) * 8;

  floatx4 zero4 = {0.f, 0.f, 0.f, 0.f};
  floatx4 acc[4][8];
#pragma unroll
  for (int a = 0; a < 4; a++)
#pragma unroll
    for (int b = 0; b < 8; b++) acc[a][b] = zero4;

  const unsigned short* w2e = w2t + (size_t)e * DIM * HID;
  const unsigned short* srcA[4];
  const unsigned short* srcB[8];
#pragma unroll
  for (int i = 0; i < 4; i++) {
    int r = w * 32 + i * 8 + lrow;
    srcA[i] = hbuf + (size_t)(row0 + r) * HID + lk;
  }
#pragma unroll
  for (int i = 0; i < 8; i++) {
    int r = w * 64 + i * 8 + lrow;
    srcB[i] = w2e + (size_t)(n0 + r) * HID + lk;
  }

  int mr = lane & 15;
  int kq = (lane >> 4) * 8;

  for (int k0 = 0; k0 < HID; k0 += TKK) {
#pragma unroll
    for (int i = 0; i < 4; i++)
      async_ld16(srcA[i] + k0, &As[(w * 32 + i * 8 + lrow) * TKK + lk]);
#pragma unroll
    for (int i = 0; i < 8; i++)
      async_ld16(srcB[i] + k0, &Bs[(w * 64 + i * 8 + lrow) * TKK + lk]);
    __syncthreads();
#pragma unroll
    for (int kk = 0; kk < TKK; kk += 32) {
      bf16x8 af[4], bfr[8];
#pragma unroll
      for (int im = 0; im < 4; im++)
        af[im] = *(const bf16x8*)&As[(wm * 64 + im * 16 + mr) * TKK + kk + kq];
#pragma unroll
      for (int in = 0; in < 8; in++)
        bfr[in] = *(const bf16x8*)&Bs[(wn * 128 + in * 16 + mr) * TKK + kk + kq];
#pragma unroll
      for (int im = 0; im < 4; im++)
#pragma unroll
        for (int in = 0; in < 8; in++)
          acc[im][in] = __builtin_amdgcn_mfma_f32_16x16x32_bf16(bfr[in], af[im], acc[im][in], 0, 0, 0);
    }
    __syncthreads();
  }
  int quad = lane >> 4;
  int c16 = lane & 15;
  const float* b2e = b2 + e * DIM;
#pragma unroll
  for (int im = 0; im < 4; im++) {
    int r = row0 + wm * 64 + im * 16 + c16;
    float gs = gate_row[r];
#pragma unroll
    for (int in = 0; in < 8; in++) {
      int c = n0 + wn * 128 + in * 16 + quad * 4;
      float4 bias = *(const float4*)&b2e[c];
      float v0 = gs * (acc[im][in][0] + bias.x);
      float v1 = gs * (acc[im][in][1] + bias.y);
      float v2 = gs * (acc[im][in][2] + bias.z);
      float v3 = gs * (acc[im][in][3] + bias.w);
      *(uint2*)&obuf[(size_t)r * DIM + c] = pack4bf(v0, v1, v2, v3);
    }
  }
}

// ---------------- combine: y[t] = obuf[pos0] + obuf[pos1] ----------------
__global__ void combine_kernel(const unsigned short* __restrict__ obuf,
                               const int* __restrict__ tok_pos,
                               float* __restrict__ y) {
  int idx = blockIdx.x * 256 + threadIdx.x;
  int t = idx >> 7;            // DIM/8 = 128 chunks per token
  int c = (idx & 127) << 3;
  int p0 = tok_pos[t * 2];
  int p1 = tok_pos[t * 2 + 1];
  uint4 a = *(const uint4*)(obuf + (size_t)p0 * DIM + c);
  uint4 b = *(const uint4*)(obuf + (size_t)p1 * DIM + c);
  float out[8];
  unsigned au[4] = {a.x, a.y, a.z, a.w};
  unsigned bu[4] = {b.x, b.y, b.z, b.w};
#pragma unroll
  for (int i = 0; i < 4; i++) {
    union { unsigned u; float f; } lo0, hi0, lo1, hi1;
    lo0.u = au[i] << 16; hi0.u = au[i] & 0xFFFF0000u;
    lo1.u = bu[i] << 16; hi1.u = bu[i] & 0xFFFF0000u;
    out[i * 2]     = lo0.f + lo1.f;
    out[i * 2 + 1] = hi0.f + hi1.f;
  }
  float* yp = y + (size_t)t * DIM + c;
  *(float4*)yp       = *(float4*)&out[0];
  *(float4*)(yp + 4) = *(float4*)&out[4];
}

// ---------------- launch ----------------
extern "C" void kernel_launch(void* const* d_in, const int* in_sizes, int n_in,
                              void* d_out, int out_size, void* d_ws, size_t ws_size,
                              hipStream_t stream) {
  const float* x  = (const float*)d_in[0];
  const float* Wg = (const float*)d_in[1];
  const float* bg = (const float*)d_in[2];
  const float* W1 = (const float*)d_in[3];
  const float* b1 = (const float*)d_in[4];
  const float* W2 = (const float*)d_in[5];
  const float* b2 = (const float*)d_in[6];
  float* y = (float*)d_out;
  char* ws = (char*)d_ws;

  constexpr size_t OFF_META = 0;                                  // cnt@0, cnt2@64, seg@128
  constexpr size_t OFF_TOKE = 256;
  constexpr size_t OFF_TOKG = OFF_TOKE + (size_t)NTOK * 2 * 4;
  constexpr size_t OFF_TPOS = OFF_TOKG + (size_t)NTOK * 2 * 4;
  constexpr size_t OFF_TROW = OFF_TPOS + (size_t)NTOK * 2 * 4;
  constexpr size_t OFF_GROW = OFF_TROW + (size_t)CAP * 4;
  constexpr size_t OFF_ZB   = OFF_GROW + (size_t)CAP * 4;
  constexpr size_t OFF_XB   = OFF_ZB  + (size_t)DIM * 2;
  constexpr size_t OFF_W1T  = OFF_XB  + (size_t)NTOK * DIM * 2;
  constexpr size_t OFF_W2T  = OFF_W1T + (size_t)NE * DIM * HID * 2;
  constexpr size_t OFF_H    = OFF_W2T + (size_t)NE * DIM * HID * 2;
  // obuf aliases xb+w1t (both dead before gemm2 runs): needs CAP*DIM*2 = 35.7MB < 50.2MB
  constexpr size_t OFF_OBUF = OFF_XB;

  int* cnt        = (int*)(ws + OFF_META);
  int* cnt2       = (int*)(ws + OFF_META + 64);
  int* seg        = (int*)(ws + OFF_META + 128);
  int* tok_e      = (int*)(ws + OFF_TOKE);
  float* tok_g    = (float*)(ws + OFF_TOKG);
  int* tok_pos    = (int*)(ws + OFF_TPOS);
  int* token_row  = (int*)(ws + OFF_TROW);
  float* gate_row = (float*)(ws + OFF_GROW);
  unsigned short* zbuf = (unsigned short*)(ws + OFF_ZB);
  unsigned short* xb   = (unsigned short*)(ws + OFF_XB);
  unsigned short* w1t  = (unsigned short*)(ws + OFF_W1T);
  unsigned short* w2t  = (unsigned short*)(ws + OFF_W2T);
  unsigned short* hbuf = (unsigned short*)(ws + OFF_H);
  unsigned short* obuf = (unsigned short*)(ws + OFF_OBUF);

  hipMemsetAsync(ws, 0, 192, stream);                       // cnt, cnt2
  hipMemsetAsync(token_row, 0xFF, (size_t)CAP * 4, stream); // token_row = -1
  hipMemsetAsync(zbuf, 0, (size_t)DIM * 2, stream);         // zero row for padding slots

  transpose_cast_kernel<<<dim3(HID / 64, DIM / 64, NE), 256, 0, stream>>>(W1, w1t, DIM, HID);
  transpose_cast_kernel<<<dim3(DIM / 64, HID / 64, NE), 256, 0, stream>>>(W2, w2t, HID, DIM);
  gating_kernel<<<NTOK / 8, 256, 0, stream>>>(x, Wg, bg, tok_e, tok_g, xb);
  count_kernel<<<NTOK * 2 / 512, 256, 0, stream>>>(tok_e, cnt);
  offsets_kernel<<<1, 64, 0, stream>>>(cnt, seg);
  route_kernel<<<NTOK / 256, 256, 0, stream>>>(tok_e, tok_g, seg, cnt2, token_row, gate_row, tok_pos);
  gemm1_kernel<<<dim3(HID / TN, CAP / TM), 256, 0, stream>>>(xb, w1t, b1, token_row, seg, zbuf, hbuf);
  gemm2_kernel<<<dim3(DIM / TN, CAP / TM), 256, 0, stream>>>(hbuf, w2t, b2, gate_row, seg, obuf);
  combine_kernel<<<NTOK * DIM / 8 / 256, 256, 0, stream>>>(obuf, tok_pos, y);
}